// Round 11
// baseline (354.914 us; speedup 1.0000x reference)
//
#include <hip/hip_runtime.h>
#include <hip/hip_bf16.h>
#include <cstdint>

// Problem dims (fixed by the reference)
#define TOKENS 8192      // BATCH*TOK = 4*2048
#define DIM_   4096
#define OUTD   4096
#define NE     8
#define NR     16
#define LORA_COLS (NE*NR)        // 128
#define KCAT  (DIM_ + LORA_COLS) // 4224
#define NTILES (KCAT/64)         // 66 K-tiles of 64
#define HSPLIT 8                 // split-K factor for the h-GEMM
#define HKC    (DIM_/HSPLIT)     // 512

typedef __attribute__((ext_vector_type(8))) short short8;
typedef __attribute__((ext_vector_type(4))) float f32x4;

__device__ __forceinline__ unsigned short f2bf(float f) {
  union { float f; unsigned u; } v; v.f = f;
  unsigned r = v.u + 0x7FFFu + ((v.u >> 16) & 1u);   // RNE
  return (unsigned short)(r >> 16);
}
__device__ __forceinline__ float bf2f(unsigned short u) {
  union { unsigned u; float f; } v; v.u = ((unsigned)u) << 16; return v.f;
}

// global -> LDS direct load, 16B per lane. LDS dest = wave-uniform base + lane*16.
__device__ __forceinline__ void load_lds16(const void* g, void* l) {
  auto gp = reinterpret_cast<const __attribute__((address_space(1))) unsigned int*>(
      reinterpret_cast<uintptr_t>(g));
  auto lp = reinterpret_cast<__attribute__((address_space(3))) unsigned int*>(
      reinterpret_cast<uintptr_t>(l));
  __builtin_amdgcn_global_load_lds(gp, lp, 16, 0, 0);
}

#define BAR() asm volatile("s_barrier" ::: "memory")
#define LGKM(N) do { asm volatile("s_waitcnt lgkmcnt(" #N ")" ::: "memory"); \
                     __builtin_amdgcn_sched_barrier(0); } while (0)
#define LGKMW(N) asm volatile("s_waitcnt lgkmcnt(" #N ")" ::: "memory")
#define VMW(N) asm volatile("s_waitcnt vmcnt(" #N ")" ::: "memory")

// ---------------------------------------------------------------------------
// Fused prep: blocks [0, OUTD+128) build Wcat/Acat; rest do x->bf16 + gating.
// (unchanged, known-correct)
// ---------------------------------------------------------------------------
__global__ __launch_bounds__(256) void fused_prep_kernel(
    const float* __restrict__ x, const float* __restrict__ Wg,
    const float* __restrict__ W, const float* __restrict__ Bm,
    const float* __restrict__ Am, unsigned short* __restrict__ Wcat,
    unsigned short* __restrict__ Acat, unsigned short* __restrict__ Xcat,
    int* __restrict__ ridx, float* __restrict__ rw, float scaling) {
  __shared__ float red[32 * 257];
  __shared__ float lg[32];
  int tid = threadIdx.x;
  int bb = blockIdx.x;
  if (bb < OUTD) {
    const float4* src = (const float4*)(W + (size_t)bb * DIM_);
    unsigned short* dst = Wcat + (size_t)bb * KCAT;
#pragma unroll
    for (int j = 0; j < DIM_ / 1024; ++j) {
      float4 v = src[j * 256 + tid];
      ushort4 o; o.x = f2bf(v.x); o.y = f2bf(v.y); o.z = f2bf(v.z); o.w = f2bf(v.w);
      *(ushort4*)(dst + (size_t)(j * 256 + tid) * 4) = o;
    }
    if (tid < LORA_COLS) {
      int e = tid >> 4, r = tid & 15;
      dst[DIM_ + tid] = f2bf(scaling * Bm[((size_t)e * OUTD + bb) * NR + r]);
    }
    return;
  }
  if (bb < OUTD + LORA_COLS) {
    int i = bb - OUTD;  // 0..127  (A is [E,R,D] flat = [128][4096])
    const float4* src = (const float4*)(Am + (size_t)i * DIM_);
    unsigned short* dst = Acat + (size_t)i * DIM_;
#pragma unroll
    for (int j = 0; j < DIM_ / 1024; ++j) {
      float4 v = src[j * 256 + tid];
      ushort4 o; o.x = f2bf(v.x); o.y = f2bf(v.y); o.z = f2bf(v.z); o.w = f2bf(v.w);
      *(ushort4*)(dst + (size_t)(j * 256 + tid) * 4) = o;
    }
    return;
  }
  // ---- prep_x body ----
  int t0 = (bb - OUTD - LORA_COLS) * 4;
  float acc[4][8];
#pragma unroll
  for (int ti = 0; ti < 4; ++ti)
#pragma unroll
    for (int e = 0; e < 8; ++e) acc[ti][e] = 0.f;
  const float4* x4 = (const float4*)x;
  const float4* wg4 = (const float4*)Wg;
#pragma unroll
  for (int j = 0; j < 4; ++j) {
    int dpos = j * 256 + tid;
    float4 wg[8];
#pragma unroll
    for (int e = 0; e < 8; ++e) wg[e] = wg4[e * 1024 + dpos];
#pragma unroll
    for (int ti = 0; ti < 4; ++ti) {
      float4 v = x4[(size_t)(t0 + ti) * 1024 + dpos];
      ushort4 o; o.x = f2bf(v.x); o.y = f2bf(v.y); o.z = f2bf(v.z); o.w = f2bf(v.w);
      *(ushort4*)&Xcat[(size_t)(t0 + ti) * KCAT + (size_t)dpos * 4] = o;
#pragma unroll
      for (int e = 0; e < 8; ++e)
        acc[ti][e] += v.x * wg[e].x + v.y * wg[e].y + v.z * wg[e].z + v.w * wg[e].w;
    }
  }
#pragma unroll
  for (int p = 0; p < 32; ++p) red[p * 257 + tid] = acc[p >> 3][p & 7];
  __syncthreads();
  {
    int p = tid >> 3, part = tid & 7;
    float s = 0.f;
#pragma unroll
    for (int i = 0; i < 32; ++i) s += red[p * 257 + part * 32 + i];
    s += __shfl_xor(s, 1);
    s += __shfl_xor(s, 2);
    s += __shfl_xor(s, 4);
    if (part == 0) lg[p] = s;
  }
  __syncthreads();
  if (tid < 4) {
    float l[8];
#pragma unroll
    for (int e = 0; e < 8; ++e) l[e] = lg[tid * 8 + e];
    int i0 = 0; float m0 = l[0];
#pragma unroll
    for (int e = 1; e < 8; ++e) if (l[e] > m0) { m0 = l[e]; i0 = e; }
    int i1 = -1; float m1 = -3.4e38f;
#pragma unroll
    for (int e = 0; e < 8; ++e) if (e != i0 && l[e] > m1) { m1 = l[e]; i1 = e; }
    float w0 = 1.0f / (1.0f + expf(m1 - m0));
    int t = t0 + tid;
    ridx[t * 2] = i0; ridx[t * 2 + 1] = i1;
    rw[t * 2] = w0;  rw[t * 2 + 1] = 1.0f - w0;
  }
}

// ---------------------------------------------------------------------------
// m97-style 128x128 GEMM, fallback h-GEMM (MODE 1) if ws too small.
// ---------------------------------------------------------------------------
template <int MODE>
__global__ __launch_bounds__(256) void gemm_kernel(
    const unsigned short* __restrict__ Aop, const unsigned short* __restrict__ Bop,
    float* __restrict__ Cout, unsigned short* __restrict__ CoutBf,
    const float* __restrict__ bias, const int* __restrict__ ridx,
    const float* __restrict__ rw,
    int M, int N, int K, int lda, int ldb, int ldc) {
  __shared__ __align__(16) unsigned short lsA[128 * 32];
  __shared__ __align__(16) unsigned short lsB[128 * 32];
  int tid = threadIdx.x;
  int lane = tid & 63, wave = tid >> 6;
  int wm = wave >> 1, wn = wave & 1;
  int row0 = blockIdx.x * 128, col0 = blockIdx.y * 128;

  f32x4 acc[4][4];
#pragma unroll
  for (int a = 0; a < 4; ++a)
#pragma unroll
    for (int b = 0; b < 4; ++b) acc[a][b] = (f32x4){0.f, 0.f, 0.f, 0.f};

  int lrow = lane >> 2;
  int lcol = (lane & 3) << 3;
  int fr = lane & 15, fk = (lane >> 4) << 3;

  const unsigned short* gA0 = Aop + (size_t)(row0 + wave * 32 + lrow) * lda + lcol;
  const unsigned short* gA1 = Aop + (size_t)(row0 + wave * 32 + 16 + lrow) * lda + lcol;
  const unsigned short* gB0 = Bop + (size_t)(col0 + wave * 32 + lrow) * ldb + lcol;
  const unsigned short* gB1 = Bop + (size_t)(col0 + wave * 32 + 16 + lrow) * ldb + lcol;

  for (int k0 = 0; k0 < K; k0 += 32) {
    load_lds16(gA0 + k0, lsA + wave * 1024);
    load_lds16(gA1 + k0, lsA + wave * 1024 + 512);
    load_lds16(gB0 + k0, lsB + wave * 1024);
    load_lds16(gB1 + k0, lsB + wave * 1024 + 512);
    __syncthreads();
    short8 af[4], bfr[4];
#pragma unroll
    for (int mi = 0; mi < 4; ++mi)
      af[mi] = *(const short8*)&lsA[(wm * 64 + mi * 16 + fr) * 32 + fk];
#pragma unroll
    for (int ni = 0; ni < 4; ++ni)
      bfr[ni] = *(const short8*)&lsB[(wn * 64 + ni * 16 + fr) * 32 + fk];
#pragma unroll
    for (int mi = 0; mi < 4; ++mi)
#pragma unroll
      for (int ni = 0; ni < 4; ++ni)
        acc[mi][ni] = __builtin_amdgcn_mfma_f32_16x16x32_bf16(af[mi], bfr[ni], acc[mi][ni], 0, 0, 0);
    __syncthreads();
  }

  int fg = lane >> 4;
  if (MODE == 0) {
#pragma unroll
    for (int ni = 0; ni < 4; ++ni) {
      int col = col0 + wn * 64 + ni * 16 + fr;
      float bv = bias[col];
#pragma unroll
      for (int mi = 0; mi < 4; ++mi)
#pragma unroll
        for (int j = 0; j < 4; ++j) {
          int row = row0 + wm * 64 + mi * 16 + fg * 4 + j;
          Cout[(size_t)row * ldc + col] = acc[mi][ni][j] + bv;
        }
    }
  } else {
#pragma unroll
    for (int mi = 0; mi < 4; ++mi)
#pragma unroll
      for (int j = 0; j < 4; ++j) {
        int row = row0 + wm * 64 + mi * 16 + fg * 4 + j;
        int i0 = ridx[row * 2], i1 = ridx[row * 2 + 1];
        float w0 = rw[row * 2], w1 = rw[row * 2 + 1];
#pragma unroll
        for (int ni = 0; ni < 4; ++ni) {
          int col = wn * 64 + ni * 16 + fr;
          int e = col >> 4;
          float w = (e == i0) ? w0 : ((e == i1) ? w1 : 0.f);
          CoutBf[(size_t)row * ldc + col] = f2bf(w * acc[mi][ni][j]);
        }
      }
  }
}

// ---------------------------------------------------------------------------
// Split-K h-GEMM: Hpart (bf16) [s][8192][128] partial sums.
// ---------------------------------------------------------------------------
__global__ __launch_bounds__(256) void gemm_h_sk_kernel(
    const unsigned short* __restrict__ Aop,   // Xcat, lda = KCAT
    const unsigned short* __restrict__ Bop,   // Acat, ldb = DIM_
    unsigned short* __restrict__ Hpart) {
  __shared__ __align__(16) unsigned short lsA[128 * 32];
  __shared__ __align__(16) unsigned short lsB[128 * 32];
  int tid = threadIdx.x;
  int lane = tid & 63, wave = tid >> 6;
  int wm = wave >> 1, wn = wave & 1;
  int row0 = blockIdx.x * 128;
  int s = blockIdx.y;
  int kbeg = s * HKC;

  f32x4 acc[4][4];
#pragma unroll
  for (int a = 0; a < 4; ++a)
#pragma unroll
    for (int b = 0; b < 4; ++b) acc[a][b] = (f32x4){0.f, 0.f, 0.f, 0.f};

  int lrow = lane >> 2;
  int lcol = (lane & 3) << 3;
  int fr = lane & 15, fk = (lane >> 4) << 3;

  const unsigned short* gA0 = Aop + (size_t)(row0 + wave * 32 + lrow) * KCAT + lcol;
  const unsigned short* gA1 = Aop + (size_t)(row0 + wave * 32 + 16 + lrow) * KCAT + lcol;
  const unsigned short* gB0 = Bop + (size_t)(wave * 32 + lrow) * DIM_ + lcol;
  const unsigned short* gB1 = Bop + (size_t)(wave * 32 + 16 + lrow) * DIM_ + lcol;

  for (int k0 = kbeg; k0 < kbeg + HKC; k0 += 32) {
    load_lds16(gA0 + k0, lsA + wave * 1024);
    load_lds16(gA1 + k0, lsA + wave * 1024 + 512);
    load_lds16(gB0 + k0, lsB + wave * 1024);
    load_lds16(gB1 + k0, lsB + wave * 1024 + 512);
    __syncthreads();
    short8 af[4], bfr[4];
#pragma unroll
    for (int mi = 0; mi < 4; ++mi)
      af[mi] = *(const short8*)&lsA[(wm * 64 + mi * 16 + fr) * 32 + fk];
#pragma unroll
    for (int ni = 0; ni < 4; ++ni)
      bfr[ni] = *(const short8*)&lsB[(wn * 64 + ni * 16 + fr) * 32 + fk];
#pragma unroll
    for (int mi = 0; mi < 4; ++mi)
#pragma unroll
      for (int ni = 0; ni < 4; ++ni)
        acc[mi][ni] = __builtin_amdgcn_mfma_f32_16x16x32_bf16(af[mi], bfr[ni], acc[mi][ni], 0, 0, 0);
    __syncthreads();
  }

  int fg = lane >> 4;
  unsigned short* outp = Hpart + (size_t)s * TOKENS * 128;
#pragma unroll
  for (int ni = 0; ni < 4; ++ni) {
    int col = wn * 64 + ni * 16 + fr;
#pragma unroll
    for (int mi = 0; mi < 4; ++mi)
#pragma unroll
      for (int j = 0; j < 4; ++j) {
        int row = row0 + wm * 64 + mi * 16 + fg * 4 + j;
        outp[(size_t)row * 128 + col] = f2bf(acc[mi][ni][j]);
      }
  }
}

// ---------------------------------------------------------------------------
// Combine split-K bf16 partials, apply routing weights, write bf16 LoRA cols.
// ---------------------------------------------------------------------------
__global__ __launch_bounds__(256) void h_combine_kernel(
    const unsigned short* __restrict__ Hpart, const int* __restrict__ ridx,
    const float* __restrict__ rw, unsigned short* __restrict__ Xcat) {
  int gid = blockIdx.x * 256 + threadIdx.x;  // over TOKENS*128
  int t = gid >> 7, c = gid & 127;
  float s = 0.f;
#pragma unroll
  for (int i = 0; i < HSPLIT; ++i) s += bf2f(Hpart[(size_t)i * TOKENS * 128 + gid]);
  int e = c >> 4;
  int i0 = ridx[t * 2], i1 = ridx[t * 2 + 1];
  float w = (e == i0) ? rw[t * 2] : ((e == i1) ? rw[t * 2 + 1] : 0.f);
  Xcat[(size_t)t * KCAT + DIM_ + c] = f2bf(w * s);
}

// ---------------------------------------------------------------------------
// Main fused GEMM R11: m201's exact quadrant schedule. 256x256 tile, BK=64,
// 8 waves (2Mx4N), st_16x32 swizzle (verified), dual-barrier phases with
// lgkmcnt(0) AFTER the barrier, Gray-code C-quadrant walk per K-tile:
//   Ph1 (miL x niL, K=64): 12 reads (A miL x2ks + B niL x2ks), lgkm(8) preBAR
//   Ph2 (miH x niL):        8 reads (A miH x2ks), B kept in regs
//   Ph3 (miH x niH):        4 reads (B niH x2ks), A kept
//   Ph4 (miL x niH):        8 reads (A miL re-read), B kept
// Staging: whole next tile (8 gload_lds) issued at Ph1; VMW(0) at Ph4
// (drain window ~3 phases > HBM latency). WAR: buf X is read through Ph4,
// stages only touch buf Y whose readers finished before the tile-boundary
// barrier.  MFMA cluster = 16 ops (4mi x 2ni x 2ks), setprio-wrapped.
// ---------------------------------------------------------------------------
#define RDA4K(dst, base, ks, mi0) do { \
  dst[0] = *(const short8*)((base) + (((mi0)+0)*2+(ks))*1024); \
  dst[1] = *(const short8*)((base) + (((mi0)+1)*2+(ks))*1024); \
  dst[2] = *(const short8*)((base) + (((mi0)+2)*2+(ks))*1024); \
  dst[3] = *(const short8*)((base) + (((mi0)+3)*2+(ks))*1024); } while (0)
#define RDB1(RB, ni, ks) (*(const short8*)(rdB0 + (RB) + (ni)*2048 + (ks)*1024))
#define MFMAQ(a0v, a1v, b0v, b1v, m0, n0) do { \
  __builtin_amdgcn_s_setprio(1); \
  _Pragma("unroll") \
  for (int mi = 0; mi < 4; ++mi) { \
    _Pragma("unroll") \
    for (int ni = 0; ni < 2; ++ni) { \
      acc[(m0)+mi][(n0)+ni] = __builtin_amdgcn_mfma_f32_16x16x32_bf16( \
          b0v[ni], a0v[mi], acc[(m0)+mi][(n0)+ni], 0, 0, 0); \
      acc[(m0)+mi][(n0)+ni] = __builtin_amdgcn_mfma_f32_16x16x32_bf16( \
          b1v[ni], a1v[mi], acc[(m0)+mi][(n0)+ni], 0, 0, 0); } } \
  __builtin_amdgcn_s_setprio(0); } while (0)
#define STAGE(srcp, kofs, dst) do { \
  load_lds16((srcp) + (kofs), (dst)); \
  load_lds16((srcp) + (kofs) + 32, (dst) + 1024); } while (0)

// One K-tile from buf RB; stage whole next tile at KN into buf SB (if DOSTAGE).
#define QTILE(RB, SB, KN, DOSTAGE) do { \
  short8 a0v[4], a1v[4], bl0[2], bl1[2], bh0[2], bh1[2]; \
  /* Ph1: quadrant miL x niL, full K=64 */ \
  RDA4K(a0v, rdA0 + (RB), 0, 0); \
  RDA4K(a1v, rdA0 + (RB), 1, 0); \
  bl0[0] = RDB1(RB, 0, 0); bl0[1] = RDB1(RB, 1, 0); \
  bl1[0] = RDB1(RB, 0, 1); bl1[1] = RDB1(RB, 1, 1); \
  if (DOSTAGE) { \
    STAGE(sA0, KN, dA0 + (SB)); STAGE(sA1, KN, dA1 + (SB)); \
    STAGE(sB0, KN, dB0 + (SB)); STAGE(sB1, KN, dB1 + (SB)); \
  } \
  LGKMW(8); \
  BAR(); LGKM(0); \
  MFMAQ(a0v, a1v, bl0, bl1, 0, 0); \
  BAR(); \
  /* Ph2: miH x niL (B kept) */ \
  RDA4K(a0v, rdA0 + (RB), 0, 4); \
  RDA4K(a1v, rdA0 + (RB), 1, 4); \
  BAR(); LGKM(0); \
  MFMAQ(a0v, a1v, bl0, bl1, 4, 0); \
  BAR(); \
  /* Ph3: miH x niH (A kept) */ \
  bh0[0] = RDB1(RB, 2, 0); bh0[1] = RDB1(RB, 3, 0); \
  bh1[0] = RDB1(RB, 2, 1); bh1[1] = RDB1(RB, 3, 1); \
  BAR(); LGKM(0); \
  MFMAQ(a0v, a1v, bh0, bh1, 4, 2); \
  BAR(); \
  /* Ph4: miL x niH (A re-read); drain stages */ \
  RDA4K(a0v, rdA0 + (RB), 0, 0); \
  RDA4K(a1v, rdA0 + (RB), 1, 0); \
  if (DOSTAGE) VMW(0); \
  BAR(); LGKM(0); \
  MFMAQ(a0v, a1v, bh0, bh1, 0, 2); \
  BAR(); \
} while (0)

__global__ __launch_bounds__(512, 2) void gemm256_kernel(
    const unsigned short* __restrict__ Aop,   // Xcat [8192][KCAT]
    const unsigned short* __restrict__ Bop,   // Wcat [4096][KCAT]
    float* __restrict__ Cout, const float* __restrict__ bias) {
  extern __shared__ char lds[];
  const int tid = threadIdx.x;
  const int lane = tid & 63, wave = tid >> 6;
  const int wm = wave >> 2, wn = wave & 3;   // 2 x 4 waves; per-wave out 128x64
  const int fr = lane & 15, kg = lane >> 4;

  // XCD-bijective block swizzle (512 % 8 == 0)
  const int bid = blockIdx.x;
  const int swz = (bid & 7) * 64 + (bid >> 3);
  const int mt = swz >> 4, nt = swz & 15;    // 32 x 16 tiles
  const int row0 = mt * 256, col0 = nt * 256;

  // ---- stage source pointers (per-thread, st_16x32 pre-swizzled cols) ----
  const int srow = lane >> 2;                                  // 0..15
  const int scol = ((lane & 3) * 8) ^ (((lane >> 5) & 1) * 16);
  const unsigned short* sA0 = Aop + (size_t)(row0 +       wave * 16 + srow) * KCAT + scol;
  const unsigned short* sA1 = Aop + (size_t)(row0 + 128 + wave * 16 + srow) * KCAT + scol;
  const unsigned short* sB0 = Bop + (size_t)(col0 +       wave * 16 + srow) * KCAT + scol;
  const unsigned short* sB1 = Bop + (size_t)(col0 + 128 + wave * 16 + srow) * KCAT + scol;

  // ---- LDS dest bases (wave-uniform; lane*16 added by HW) ----
  char* dA0 = lds +      0 + wave * 2048;
  char* dA1 = lds +  16384 + wave * 2048;
  char* dB0 = lds +  32768 + wave * 2048;
  char* dB1 = lds +  49152 + wave * 2048;

  // ---- ds_read bases (swizzled) ----
  const int swzo = (kg * 16) ^ ((fr >> 3) << 5);
  const char* rdA0 = lds + wm * 16384 + fr * 64 + swzo;
  const char* rdB0 = lds + 32768 + (wn >> 1) * 16384 + (wn & 1) * 8192 + fr * 64 + swzo;

  f32x4 acc[8][4];
#pragma unroll
  for (int a = 0; a < 8; ++a)
#pragma unroll
    for (int b = 0; b < 4; ++b) acc[a][b] = (f32x4){0.f, 0.f, 0.f, 0.f};

  // ---- prologue: stage tile 0 -> buf0 ----
  STAGE(sA0, 0, dA0); STAGE(sA1, 0, dA1);
  STAGE(sB0, 0, dB0); STAGE(sB1, 0, dB1);
  VMW(0);
  BAR();

  // ---- main loop: tile pairs (0,1)..(62,63) ----
  for (int i = 0; i < NTILES / 2 - 1; ++i) {
    QTILE(0,     65536, (2 * i + 1) * 64, true);   // tile 2i (buf0), stage 2i+1
    QTILE(65536, 0,     (2 * i + 2) * 64, true);   // tile 2i+1 (buf1), stage 2i+2
  }
  // tile 64 (buf0), stage tile 65 -> buf1; tile 65 (buf1), no stage
  QTILE(0, 65536, 65 * 64, true);
  QTILE(65536, 0, 0, false);

  // ---- C write (transposed fragments: lane holds 4 consecutive cols) ----
#pragma unroll
  for (int ni = 0; ni < 4; ++ni) {
    int colb = col0 + wn * 64 + ni * 16 + kg * 4;
    float4 bv = *(const float4*)&bias[colb];
#pragma unroll
    for (int mi = 0; mi < 8; ++mi) {
      int row = row0 + wm * 128 + mi * 16 + fr;
      float4 v;
      v.x = acc[mi][ni][0] + bv.x;
      v.y = acc[mi][ni][1] + bv.y;
      v.z = acc[mi][ni][2] + bv.z;
      v.w = acc[mi][ni][3] + bv.w;
      *(float4*)&Cout[(size_t)row * OUTD + colb] = v;
    }
  }
}

// ---------------------------------------------------------------------------
extern "C" void kernel_launch(void* const* d_in, const int* in_sizes, int n_in,
                              void* d_out, int out_size, void* d_ws, size_t ws_size,
                              hipStream_t stream) {
  const float* x  = (const float*)d_in[0];
  const float* Wb = (const float*)d_in[1];
  const float* bb = (const float*)d_in[2];
  const float* Wg = (const float*)d_in[3];
  const float* Am = (const float*)d_in[4];
  const float* Bm = (const float*)d_in[5];
  float* out = (float*)d_out;

  unsigned short* Wcat = (unsigned short*)d_ws;                 // [OUTD][KCAT]
  unsigned short* Xcat = Wcat + (size_t)OUTD * KCAT;            // [TOKENS][KCAT]
  unsigned short* Acat = Xcat + (size_t)TOKENS * KCAT;          // [128][DIM]
  int*   ridx = (int*)(Acat + (size_t)LORA_COLS * DIM_);        // [TOKENS][2]
  float* rw   = (float*)(ridx + (size_t)TOKENS * 2);            // [TOKENS][2]
  unsigned short* Hpart = (unsigned short*)(rw + (size_t)TOKENS * 2); // [S][TOKENS][128] bf16

  const size_t ws_needed = (size_t)((char*)(Hpart + (size_t)HSPLIT * TOKENS * 128)
                                    - (char*)d_ws);
  const bool use_splitk = (ws_size >= ws_needed);

  const float scaling = 16.0f / (float)NR;  // = 1.0

  hipFuncSetAttribute((const void*)gemm256_kernel,
                      hipFuncAttributeMaxDynamicSharedMemorySize, 131072);

  fused_prep_kernel<<<dim3(OUTD + LORA_COLS + TOKENS / 4), dim3(256), 0, stream>>>(
      x, Wg, Wb, Bm, Am, Wcat, Acat, Xcat, ridx, rw, scaling);
  if (use_splitk) {
    gemm_h_sk_kernel<<<dim3(TOKENS / 128, HSPLIT), dim3(256), 0, stream>>>(
        Xcat, Acat, Hpart);
    h_combine_kernel<<<dim3(TOKENS * 128 / 256), dim3(256), 0, stream>>>(
        Hpart, ridx, rw, Xcat);
  } else {
    gemm_kernel<1><<<dim3(TOKENS / 128, 1), dim3(256), 0, stream>>>(
        Xcat, Acat, (float*)nullptr, Xcat + DIM_, (const float*)nullptr,
        ridx, rw, TOKENS, LORA_COLS, DIM_, KCAT, DIM_, KCAT);
  }
  // main fused GEMM: 256x256, quadrant Gray-code 8-phase (m201 schedule)
  gemm256_kernel<<<dim3(512), dim3(512), 131072, stream>>>(Xcat, Wcat, out, bb);
}

// Round 12
// 312.752 us; speedup vs baseline: 1.1348x; 1.1348x over previous
//
#include <hip/hip_runtime.h>
#include <hip/hip_bf16.h>
#include <cstdint>

// Problem dims (fixed by the reference)
#define TOKENS 8192      // BATCH*TOK = 4*2048
#define DIM_   4096
#define OUTD   4096
#define NE     8
#define NR     16
#define LORA_COLS (NE*NR)        // 128
#define KCAT  (DIM_ + LORA_COLS) // 4224
#define NTILES (KCAT/64)         // 66 K-tiles of 64
#define HSPLIT 8                 // split-K factor for the h-GEMM
#define HKC    (DIM_/HSPLIT)     // 512

typedef __attribute__((ext_vector_type(8))) short short8;
typedef __attribute__((ext_vector_type(4))) float f32x4;

__device__ __forceinline__ unsigned short f2bf(float f) {
  union { float f; unsigned u; } v; v.f = f;
  unsigned r = v.u + 0x7FFFu + ((v.u >> 16) & 1u);   // RNE
  return (unsigned short)(r >> 16);
}
__device__ __forceinline__ float bf2f(unsigned short u) {
  union { unsigned u; float f; } v; v.u = ((unsigned)u) << 16; return v.f;
}

// global -> LDS direct load, 16B per lane. LDS dest = wave-uniform base + lane*16.
__device__ __forceinline__ void load_lds16(const void* g, void* l) {
  auto gp = reinterpret_cast<const __attribute__((address_space(1))) unsigned int*>(
      reinterpret_cast<uintptr_t>(g));
  auto lp = reinterpret_cast<__attribute__((address_space(3))) unsigned int*>(
      reinterpret_cast<uintptr_t>(l));
  __builtin_amdgcn_global_load_lds(gp, lp, 16, 0, 0);
}

#define BAR() asm volatile("s_barrier" ::: "memory")
#define LGKM(N) do { asm volatile("s_waitcnt lgkmcnt(" #N ")" ::: "memory"); \
                     __builtin_amdgcn_sched_barrier(0); } while (0)
#define VMW(N) asm volatile("s_waitcnt vmcnt(" #N ")" ::: "memory")

// ---------------------------------------------------------------------------
// Fused prep: blocks [0, OUTD+128) build Wcat/Acat; rest do x->bf16 + gating.
// ---------------------------------------------------------------------------
__global__ __launch_bounds__(256) void fused_prep_kernel(
    const float* __restrict__ x, const float* __restrict__ Wg,
    const float* __restrict__ W, const float* __restrict__ Bm,
    const float* __restrict__ Am, unsigned short* __restrict__ Wcat,
    unsigned short* __restrict__ Acat, unsigned short* __restrict__ Xcat,
    int* __restrict__ ridx, float* __restrict__ rw, float scaling) {
  __shared__ float red[32 * 257];
  __shared__ float lg[32];
  int tid = threadIdx.x;
  int bb = blockIdx.x;
  if (bb < OUTD) {
    const float4* src = (const float4*)(W + (size_t)bb * DIM_);
    unsigned short* dst = Wcat + (size_t)bb * KCAT;
#pragma unroll
    for (int j = 0; j < DIM_ / 1024; ++j) {
      float4 v = src[j * 256 + tid];
      ushort4 o; o.x = f2bf(v.x); o.y = f2bf(v.y); o.z = f2bf(v.z); o.w = f2bf(v.w);
      *(ushort4*)(dst + (size_t)(j * 256 + tid) * 4) = o;
    }
    if (tid < LORA_COLS) {
      int e = tid >> 4, r = tid & 15;
      dst[DIM_ + tid] = f2bf(scaling * Bm[((size_t)e * OUTD + bb) * NR + r]);
    }
    return;
  }
  if (bb < OUTD + LORA_COLS) {
    int i = bb - OUTD;  // 0..127  (A is [E,R,D] flat = [128][4096])
    const float4* src = (const float4*)(Am + (size_t)i * DIM_);
    unsigned short* dst = Acat + (size_t)i * DIM_;
#pragma unroll
    for (int j = 0; j < DIM_ / 1024; ++j) {
      float4 v = src[j * 256 + tid];
      ushort4 o; o.x = f2bf(v.x); o.y = f2bf(v.y); o.z = f2bf(v.z); o.w = f2bf(v.w);
      *(ushort4*)(dst + (size_t)(j * 256 + tid) * 4) = o;
    }
    return;
  }
  // ---- prep_x body ----
  int t0 = (bb - OUTD - LORA_COLS) * 4;
  float acc[4][8];
#pragma unroll
  for (int ti = 0; ti < 4; ++ti)
#pragma unroll
    for (int e = 0; e < 8; ++e) acc[ti][e] = 0.f;
  const float4* x4 = (const float4*)x;
  const float4* wg4 = (const float4*)Wg;
#pragma unroll
  for (int j = 0; j < 4; ++j) {
    int dpos = j * 256 + tid;
    float4 wg[8];
#pragma unroll
    for (int e = 0; e < 8; ++e) wg[e] = wg4[e * 1024 + dpos];
#pragma unroll
    for (int ti = 0; ti < 4; ++ti) {
      float4 v = x4[(size_t)(t0 + ti) * 1024 + dpos];
      ushort4 o; o.x = f2bf(v.x); o.y = f2bf(v.y); o.z = f2bf(v.z); o.w = f2bf(v.w);
      *(ushort4*)&Xcat[(size_t)(t0 + ti) * KCAT + (size_t)dpos * 4] = o;
#pragma unroll
      for (int e = 0; e < 8; ++e)
        acc[ti][e] += v.x * wg[e].x + v.y * wg[e].y + v.z * wg[e].z + v.w * wg[e].w;
    }
  }
#pragma unroll
  for (int p = 0; p < 32; ++p) red[p * 257 + tid] = acc[p >> 3][p & 7];
  __syncthreads();
  {
    int p = tid >> 3, part = tid & 7;
    float s = 0.f;
#pragma unroll
    for (int i = 0; i < 32; ++i) s += red[p * 257 + part * 32 + i];
    s += __shfl_xor(s, 1);
    s += __shfl_xor(s, 2);
    s += __shfl_xor(s, 4);
    if (part == 0) lg[p] = s;
  }
  __syncthreads();
  if (tid < 4) {
    float l[8];
#pragma unroll
    for (int e = 0; e < 8; ++e) l[e] = lg[tid * 8 + e];
    int i0 = 0; float m0 = l[0];
#pragma unroll
    for (int e = 1; e < 8; ++e) if (l[e] > m0) { m0 = l[e]; i0 = e; }
    int i1 = -1; float m1 = -3.4e38f;
#pragma unroll
    for (int e = 0; e < 8; ++e) if (e != i0 && l[e] > m1) { m1 = l[e]; i1 = e; }
    float w0 = 1.0f / (1.0f + expf(m1 - m0));
    int t = t0 + tid;
    ridx[t * 2] = i0; ridx[t * 2 + 1] = i1;
    rw[t * 2] = w0;  rw[t * 2 + 1] = 1.0f - w0;
  }
}

// ---------------------------------------------------------------------------
// m97-style 128x128 GEMM, fallback h-GEMM (MODE 1) if ws too small.
// ---------------------------------------------------------------------------
template <int MODE>
__global__ __launch_bounds__(256) void gemm_kernel(
    const unsigned short* __restrict__ Aop, const unsigned short* __restrict__ Bop,
    float* __restrict__ Cout, unsigned short* __restrict__ CoutBf,
    const float* __restrict__ bias, const int* __restrict__ ridx,
    const float* __restrict__ rw,
    int M, int N, int K, int lda, int ldb, int ldc) {
  __shared__ __align__(16) unsigned short lsA[128 * 32];
  __shared__ __align__(16) unsigned short lsB[128 * 32];
  int tid = threadIdx.x;
  int lane = tid & 63, wave = tid >> 6;
  int wm = wave >> 1, wn = wave & 1;
  int row0 = blockIdx.x * 128, col0 = blockIdx.y * 128;

  f32x4 acc[4][4];
#pragma unroll
  for (int a = 0; a < 4; ++a)
#pragma unroll
    for (int b = 0; b < 4; ++b) acc[a][b] = (f32x4){0.f, 0.f, 0.f, 0.f};

  int lrow = lane >> 2;
  int lcol = (lane & 3) << 3;
  int fr = lane & 15, fk = (lane >> 4) << 3;

  const unsigned short* gA0 = Aop + (size_t)(row0 + wave * 32 + lrow) * lda + lcol;
  const unsigned short* gA1 = Aop + (size_t)(row0 + wave * 32 + 16 + lrow) * lda + lcol;
  const unsigned short* gB0 = Bop + (size_t)(col0 + wave * 32 + lrow) * ldb + lcol;
  const unsigned short* gB1 = Bop + (size_t)(col0 + wave * 32 + 16 + lrow) * ldb + lcol;

  for (int k0 = 0; k0 < K; k0 += 32) {
    load_lds16(gA0 + k0, lsA + wave * 1024);
    load_lds16(gA1 + k0, lsA + wave * 1024 + 512);
    load_lds16(gB0 + k0, lsB + wave * 1024);
    load_lds16(gB1 + k0, lsB + wave * 1024 + 512);
    __syncthreads();
    short8 af[4], bfr[4];
#pragma unroll
    for (int mi = 0; mi < 4; ++mi)
      af[mi] = *(const short8*)&lsA[(wm * 64 + mi * 16 + fr) * 32 + fk];
#pragma unroll
    for (int ni = 0; ni < 4; ++ni)
      bfr[ni] = *(const short8*)&lsB[(wn * 64 + ni * 16 + fr) * 32 + fk];
#pragma unroll
    for (int mi = 0; mi < 4; ++mi)
#pragma unroll
      for (int ni = 0; ni < 4; ++ni)
        acc[mi][ni] = __builtin_amdgcn_mfma_f32_16x16x32_bf16(af[mi], bfr[ni], acc[mi][ni], 0, 0, 0);
    __syncthreads();
  }

  int fg = lane >> 4;
  if (MODE == 0) {
#pragma unroll
    for (int ni = 0; ni < 4; ++ni) {
      int col = col0 + wn * 64 + ni * 16 + fr;
      float bv = bias[col];
#pragma unroll
      for (int mi = 0; mi < 4; ++mi)
#pragma unroll
        for (int j = 0; j < 4; ++j) {
          int row = row0 + wm * 64 + mi * 16 + fg * 4 + j;
          Cout[(size_t)row * ldc + col] = acc[mi][ni][j] + bv;
        }
    }
  } else {
#pragma unroll
    for (int mi = 0; mi < 4; ++mi)
#pragma unroll
      for (int j = 0; j < 4; ++j) {
        int row = row0 + wm * 64 + mi * 16 + fg * 4 + j;
        int i0 = ridx[row * 2], i1 = ridx[row * 2 + 1];
        float w0 = rw[row * 2], w1 = rw[row * 2 + 1];
#pragma unroll
        for (int ni = 0; ni < 4; ++ni) {
          int col = wn * 64 + ni * 16 + fr;
          int e = col >> 4;
          float w = (e == i0) ? w0 : ((e == i1) ? w1 : 0.f);
          CoutBf[(size_t)row * ldc + col] = f2bf(w * acc[mi][ni][j]);
        }
      }
  }
}

// ---------------------------------------------------------------------------
// Split-K h-GEMM: Hpart (bf16) [s][8192][128] partial sums.
// ---------------------------------------------------------------------------
__global__ __launch_bounds__(256) void gemm_h_sk_kernel(
    const unsigned short* __restrict__ Aop,   // Xcat, lda = KCAT
    const unsigned short* __restrict__ Bop,   // Acat, ldb = DIM_
    unsigned short* __restrict__ Hpart) {
  __shared__ __align__(16) unsigned short lsA[128 * 32];
  __shared__ __align__(16) unsigned short lsB[128 * 32];
  int tid = threadIdx.x;
  int lane = tid & 63, wave = tid >> 6;
  int wm = wave >> 1, wn = wave & 1;
  int row0 = blockIdx.x * 128;
  int s = blockIdx.y;
  int kbeg = s * HKC;

  f32x4 acc[4][4];
#pragma unroll
  for (int a = 0; a < 4; ++a)
#pragma unroll
    for (int b = 0; b < 4; ++b) acc[a][b] = (f32x4){0.f, 0.f, 0.f, 0.f};

  int lrow = lane >> 2;
  int lcol = (lane & 3) << 3;
  int fr = lane & 15, fk = (lane >> 4) << 3;

  const unsigned short* gA0 = Aop + (size_t)(row0 + wave * 32 + lrow) * KCAT + lcol;
  const unsigned short* gA1 = Aop + (size_t)(row0 + wave * 32 + 16 + lrow) * KCAT + lcol;
  const unsigned short* gB0 = Bop + (size_t)(wave * 32 + lrow) * DIM_ + lcol;
  const unsigned short* gB1 = Bop + (size_t)(wave * 32 + 16 + lrow) * DIM_ + lcol;

  for (int k0 = kbeg; k0 < kbeg + HKC; k0 += 32) {
    load_lds16(gA0 + k0, lsA + wave * 1024);
    load_lds16(gA1 + k0, lsA + wave * 1024 + 512);
    load_lds16(gB0 + k0, lsB + wave * 1024);
    load_lds16(gB1 + k0, lsB + wave * 1024 + 512);
    __syncthreads();
    short8 af[4], bfr[4];
#pragma unroll
    for (int mi = 0; mi < 4; ++mi)
      af[mi] = *(const short8*)&lsA[(wm * 64 + mi * 16 + fr) * 32 + fk];
#pragma unroll
    for (int ni = 0; ni < 4; ++ni)
      bfr[ni] = *(const short8*)&lsB[(wn * 64 + ni * 16 + fr) * 32 + fk];
#pragma unroll
    for (int mi = 0; mi < 4; ++mi)
#pragma unroll
      for (int ni = 0; ni < 4; ++ni)
        acc[mi][ni] = __builtin_amdgcn_mfma_f32_16x16x32_bf16(af[mi], bfr[ni], acc[mi][ni], 0, 0, 0);
    __syncthreads();
  }

  int fg = lane >> 4;
  unsigned short* outp = Hpart + (size_t)s * TOKENS * 128;
#pragma unroll
  for (int ni = 0; ni < 4; ++ni) {
    int col = wn * 64 + ni * 16 + fr;
#pragma unroll
    for (int mi = 0; mi < 4; ++mi)
#pragma unroll
      for (int j = 0; j < 4; ++j) {
        int row = row0 + wm * 64 + mi * 16 + fg * 4 + j;
        outp[(size_t)row * 128 + col] = f2bf(acc[mi][ni][j]);
      }
  }
}

// ---------------------------------------------------------------------------
// Combine split-K bf16 partials, apply routing weights, write bf16 LoRA cols.
// ---------------------------------------------------------------------------
__global__ __launch_bounds__(256) void h_combine_kernel(
    const unsigned short* __restrict__ Hpart, const int* __restrict__ ridx,
    const float* __restrict__ rw, unsigned short* __restrict__ Xcat) {
  int gid = blockIdx.x * 256 + threadIdx.x;  // over TOKENS*128
  int t = gid >> 7, c = gid & 127;
  float s = 0.f;
#pragma unroll
  for (int i = 0; i < HSPLIT; ++i) s += bf2f(Hpart[(size_t)i * TOKENS * 128 + gid]);
  int e = c >> 4;
  int i0 = ridx[t * 2], i1 = ridx[t * 2 + 1];
  float w = (e == i0) ? rw[t * 2] : ((e == i1) ? rw[t * 2 + 1] : 0.f);
  Xcat[(size_t)t * KCAT + DIM_ + c] = f2bf(w * s);
}

// ---------------------------------------------------------------------------
// Main fused GEMM (best-known R5/R10 structure): 256x256 tile, BK=64, 8 waves
// (2Mx4N), 8-phase schedule, st_16x32 LDS swizzle, setprio around MFMA,
// operand prefetch 1 phase ahead, 3-deep stage pipeline with VMW(6) at P4/P8.
// Campaign (R3-R11): vmcnt rotation (null), 1-barrier counted-lgkm (null),
// B-to-reg (-65%), 32x32 MFMA (-20%, bank conflicts), quadrant Gray-code
// (-28%, L2 thrash) -> this schedule is the verified local optimum; its
// LDS-read pipe (conflict-free only in this 16x16 read pattern) is binding.
// ---------------------------------------------------------------------------
#define RD_A4(dst, base, ks, mi0) do { \
  dst[0] = *(const short8*)((base) + (((mi0)+0)*2+(ks))*1024); \
  dst[1] = *(const short8*)((base) + (((mi0)+1)*2+(ks))*1024); \
  dst[2] = *(const short8*)((base) + (((mi0)+2)*2+(ks))*1024); \
  dst[3] = *(const short8*)((base) + (((mi0)+3)*2+(ks))*1024); } while (0)
#define RD_B4(dst, base, ks) do { \
  dst[0] = *(const short8*)((base) + 0*2048 + (ks)*1024); \
  dst[1] = *(const short8*)((base) + 1*2048 + (ks)*1024); \
  dst[2] = *(const short8*)((base) + 2*2048 + (ks)*1024); \
  dst[3] = *(const short8*)((base) + 3*2048 + (ks)*1024); } while (0)
#define MFMA_BLK(a4, b4, m0) do { \
  __builtin_amdgcn_s_setprio(1); \
  _Pragma("unroll") \
  for (int mi = 0; mi < 4; ++mi) { \
    _Pragma("unroll") \
    for (int ni = 0; ni < 4; ++ni) { \
      acc[(m0)+mi][ni] = __builtin_amdgcn_mfma_f32_16x16x32_bf16( \
          b4[ni], a4[mi], acc[(m0)+mi][ni], 0, 0, 0); } } \
  __builtin_amdgcn_s_setprio(0); } while (0)
#define STAGE(srcp, kofs, dst) do { \
  load_lds16((srcp) + (kofs), (dst)); \
  load_lds16((srcp) + (kofs) + 32, (dst) + 1024); } while (0)

__global__ __launch_bounds__(512, 2) void gemm256_kernel(
    const unsigned short* __restrict__ Aop,   // Xcat [8192][KCAT]
    const unsigned short* __restrict__ Bop,   // Wcat [4096][KCAT]
    float* __restrict__ Cout, const float* __restrict__ bias) {
  extern __shared__ char lds[];
  const int tid = threadIdx.x;
  const int lane = tid & 63, wave = tid >> 6;
  const int wm = wave >> 2, wn = wave & 3;   // 2 x 4 waves; per-wave out 128x64
  const int fr = lane & 15, kg = lane >> 4;

  // XCD-bijective block swizzle (512 % 8 == 0)
  const int bid = blockIdx.x;
  const int swz = (bid & 7) * 64 + (bid >> 3);
  const int mt = swz >> 4, nt = swz & 15;    // 32 x 16 tiles
  const int row0 = mt * 256, col0 = nt * 256;

  // ---- stage source pointers (per-thread, st_16x32 pre-swizzled cols) ----
  const int srow = lane >> 2;                                  // 0..15
  const int scol = ((lane & 3) * 8) ^ (((lane >> 5) & 1) * 16);
  const unsigned short* sA0 = Aop + (size_t)(row0 +       wave * 16 + srow) * KCAT + scol;
  const unsigned short* sA1 = Aop + (size_t)(row0 + 128 + wave * 16 + srow) * KCAT + scol;
  const unsigned short* sB0 = Bop + (size_t)(col0 +       wave * 16 + srow) * KCAT + scol;
  const unsigned short* sB1 = Bop + (size_t)(col0 + 128 + wave * 16 + srow) * KCAT + scol;

  // ---- LDS dest bases (wave-uniform; lane*16 added by HW) ----
  char* dA0b0 = lds +      0 + wave * 2048;
  char* dA1b0 = lds +  16384 + wave * 2048;
  char* dB0b0 = lds +  32768 + wave * 2048;
  char* dB1b0 = lds +  49152 + wave * 2048;
  char* dA0b1 = dA0b0 + 65536;
  char* dA1b1 = dA1b0 + 65536;
  char* dB0b1 = dB0b0 + 65536;
  char* dB1b1 = dB1b0 + 65536;

  // ---- ds_read bases (swizzled) ----
  const int swzo = (kg * 16) ^ ((fr >> 3) << 5);
  const char* rdA0 = lds + wm * 16384 + fr * 64 + swzo;
  const char* rdA1 = rdA0 + 65536;
  const char* rdB0 = lds + 32768 + (wn >> 1) * 16384 + (wn & 1) * 8192 + fr * 64 + swzo;
  const char* rdB1 = rdB0 + 65536;

  f32x4 acc[8][4];
#pragma unroll
  for (int a = 0; a < 8; ++a)
#pragma unroll
    for (int b = 0; b < 4; ++b) acc[a][b] = (f32x4){0.f, 0.f, 0.f, 0.f};

  short8 aL[4], aH[4], a1L[4], a1H[4], b0f[4], b1f[4];

  // ---- prologue: tile0 full -> buf0; tile1 {B0,B1,A0} -> buf1 (A1b1 at P1);
  //      VMW(6) drains the 8 tile0 loads; preload P1 operands ----
  STAGE(sA0, 0, dA0b0); STAGE(sA1, 0, dA1b0);
  STAGE(sB0, 0, dB0b0); STAGE(sB1, 0, dB1b0);
  STAGE(sB0, 64, dB0b1); STAGE(sB1, 64, dB1b1); STAGE(sA0, 64, dA0b1);
  VMW(6);
  BAR();
  RD_A4(aL, rdA0, 0, 0); RD_B4(b0f, rdB0, 0);

  // ---- main loop: 32 iterations, tile pairs (0,1)..(62,63) ----
  for (int i = 0; i < NTILES / 2 - 1; ++i) {
    const int k1 = (2 * i + 1) * 64, k2 = k1 + 64, k3 = k1 + 128;
    // P1: MFMA tile 2i (buf0) q0; prefetch aH,b1f; stage A1b1@k1
    RD_A4(aH, rdA0, 0, 4); RD_B4(b1f, rdB0, 1);
    STAGE(sA1, k1, dA1b1);
    BAR(); LGKM(8);
    MFMA_BLK(aL, b0f, 0);
    BAR();
    // P2: q1; prefetch a1L; stage B0b0@k2
    RD_A4(a1L, rdA0, 1, 0);
    STAGE(sB0, k2, dB0b0);
    BAR(); LGKM(4);
    MFMA_BLK(aH, b0f, 4);
    BAR();
    // P3: q2; prefetch a1H; stage B1b0@k2
    RD_A4(a1H, rdA0, 1, 4);
    STAGE(sB1, k2, dB1b0);
    BAR(); LGKM(4);
    MFMA_BLK(a1L, b1f, 0);
    BAR();
    // P4: stage A0b0@k2; VMW(6) -> buf1 tile 2i+1 ready; prefetch its q0
    STAGE(sA0, k2, dA0b0);
    VMW(6);
    BAR();
    RD_A4(aL, rdA1, 0, 0); RD_B4(b0f, rdB1, 0);
    LGKM(8);
    MFMA_BLK(a1H, b1f, 4);
    BAR();
    // P5: tile 2i+1 (buf1) q0; prefetch aH,b1f; stage A1b0@k2
    RD_A4(aH, rdA1, 0, 4); RD_B4(b1f, rdB1, 1);
    STAGE(sA1, k2, dA1b0);
    BAR(); LGKM(8);
    MFMA_BLK(aL, b0f, 0);
    BAR();
    // P6: stage B0b1@k3
    RD_A4(a1L, rdA1, 1, 0);
    STAGE(sB0, k3, dB0b1);
    BAR(); LGKM(4);
    MFMA_BLK(aH, b0f, 4);
    BAR();
    // P7: stage B1b1@k3
    RD_A4(a1H, rdA1, 1, 4);
    STAGE(sB1, k3, dB1b1);
    BAR(); LGKM(4);
    MFMA_BLK(a1L, b1f, 0);
    BAR();
    // P8: stage A0b1@k3; VMW(6) -> buf0 tile 2i+2 ready; prefetch its q0
    STAGE(sA0, k3, dA0b1);
    VMW(6);
    BAR();
    RD_A4(aL, rdA0, 0, 0); RD_B4(b0f, rdB0, 0);
    LGKM(8);
    MFMA_BLK(a1H, b1f, 4);
    BAR();
  }

  // ---- epilogue: tile 64 (buf0; stage A1b1@65), tile 65 (buf1) ----
  {
    const int k65 = 65 * 64;
    // E1
    RD_A4(aH, rdA0, 0, 4); RD_B4(b1f, rdB0, 1);
    STAGE(sA1, k65, dA1b1);
    BAR(); LGKM(8);
    MFMA_BLK(aL, b0f, 0);
    BAR();
    // E2
    RD_A4(a1L, rdA0, 1, 0);
    BAR(); LGKM(4);
    MFMA_BLK(aH, b0f, 4);
    BAR();
    // E3
    RD_A4(a1H, rdA0, 1, 4);
    BAR(); LGKM(4);
    MFMA_BLK(a1L, b1f, 0);
    BAR();
    // E4: drain ALL stages; buf1 tile 65 complete
    VMW(0);
    BAR();
    RD_A4(aL, rdA1, 0, 0); RD_B4(b0f, rdB1, 0);
    LGKM(8);
    MFMA_BLK(a1H, b1f, 4);
    BAR();
    // tile 65 (no stages, no barriers)
    RD_A4(aH, rdA1, 0, 4); RD_B4(b1f, rdB1, 1);
    LGKM(8);
    MFMA_BLK(aL, b0f, 0);
    RD_A4(a1L, rdA1, 1, 0);
    LGKM(4);
    MFMA_BLK(aH, b0f, 4);
    RD_A4(a1H, rdA1, 1, 4);
    LGKM(4);
    MFMA_BLK(a1L, b1f, 0);
    LGKM(0);
    MFMA_BLK(a1H, b1f, 4);
  }

  // ---- C write (transposed fragments: lane holds 4 consecutive cols) ----
#pragma unroll
  for (int ni = 0; ni < 4; ++ni) {
    int colb = col0 + wn * 64 + ni * 16 + kg * 4;
    float4 bv = *(const float4*)&bias[colb];
#pragma unroll
    for (int mi = 0; mi < 8; ++mi) {
      int row = row0 + wm * 128 + mi * 16 + fr;
      float4 v;
      v.x = acc[mi][ni][0] + bv.x;
      v.y = acc[mi][ni][1] + bv.y;
      v.z = acc[mi][ni][2] + bv.z;
      v.w = acc[mi][ni][3] + bv.w;
      *(float4*)&Cout[(size_t)row * OUTD + colb] = v;
    }
  }
}

// ---------------------------------------------------------------------------
extern "C" void kernel_launch(void* const* d_in, const int* in_sizes, int n_in,
                              void* d_out, int out_size, void* d_ws, size_t ws_size,
                              hipStream_t stream) {
  const float* x  = (const float*)d_in[0];
  const float* Wb = (const float*)d_in[1];
  const float* bb = (const float*)d_in[2];
  const float* Wg = (const float*)d_in[3];
  const float* Am = (const float*)d_in[4];
  const float* Bm = (const float*)d_in[5];
  float* out = (float*)d_out;

  unsigned short* Wcat = (unsigned short*)d_ws;                 // [OUTD][KCAT]
  unsigned short* Xcat = Wcat + (size_t)OUTD * KCAT;            // [TOKENS][KCAT]
  unsigned short* Acat = Xcat + (size_t)TOKENS * KCAT;          // [128][DIM]
  int*   ridx = (int*)(Acat + (size_t)LORA_COLS * DIM_);        // [TOKENS][2]
  float* rw   = (float*)(ridx + (size_t)TOKENS * 2);            // [TOKENS][2]
  unsigned short* Hpart = (unsigned short*)(rw + (size_t)TOKENS * 2); // [S][TOKENS][128] bf16

  const size_t ws_needed = (size_t)((char*)(Hpart + (size_t)HSPLIT * TOKENS * 128)
                                    - (char*)d_ws);
  const bool use_splitk = (ws_size >= ws_needed);

  const float scaling = 16.0f / (float)NR;  // = 1.0

  hipFuncSetAttribute((const void*)gemm256_kernel,
                      hipFuncAttributeMaxDynamicSharedMemorySize, 131072);

  fused_prep_kernel<<<dim3(OUTD + LORA_COLS + TOKENS / 4), dim3(256), 0, stream>>>(
      x, Wg, Wb, Bm, Am, Wcat, Acat, Xcat, ridx, rw, scaling);
  if (use_splitk) {
    gemm_h_sk_kernel<<<dim3(TOKENS / 128, HSPLIT), dim3(256), 0, stream>>>(
        Xcat, Acat, Hpart);
    h_combine_kernel<<<dim3(TOKENS * 128 / 256), dim3(256), 0, stream>>>(
        Hpart, ridx, rw, Xcat);
  } else {
    gemm_kernel<1><<<dim3(TOKENS / 128, 1), dim3(256), 0, stream>>>(
        Xcat, Acat, (float*)nullptr, Xcat + DIM_, (const float*)nullptr,
        ridx, rw, TOKENS, LORA_COLS, DIM_, KCAT, DIM_, KCAT);
  }
  // main fused GEMM: 256x256 8-phase, 3-deep stage pipeline (vmcnt(6))
  gemm256_kernel<<<dim3(512), dim3(512), 131072, stream>>>(Xcat, Wcat, out, bb);
}

// Round 13
// 310.407 us; speedup vs baseline: 1.1434x; 1.0076x over previous
//
#include <hip/hip_runtime.h>
#include <hip/hip_bf16.h>
#include <cstdint>

// Problem dims (fixed by the reference)
#define TOKENS 8192      // BATCH*TOK = 4*2048
#define DIM_   4096
#define OUTD   4096
#define NE     8
#define NR     16
#define LORA_COLS (NE*NR)        // 128
#define KCAT  (DIM_ + LORA_COLS) // 4224
#define NTILES (KCAT/64)         // 66 K-tiles of 64
#define HSPLIT 8                 // split-K factor for the h-GEMM
#define HKC    (DIM_/HSPLIT)     // 512

typedef __attribute__((ext_vector_type(8))) short short8;
typedef __attribute__((ext_vector_type(4))) float f32x4;

__device__ __forceinline__ unsigned short f2bf(float f) {
  union { float f; unsigned u; } v; v.f = f;
  unsigned r = v.u + 0x7FFFu + ((v.u >> 16) & 1u);   // RNE
  return (unsigned short)(r >> 16);
}
__device__ __forceinline__ float bf2f(unsigned short u) {
  union { unsigned u; float f; } v; v.u = ((unsigned)u) << 16; return v.f;
}

// global -> LDS direct load, 16B per lane. LDS dest = wave-uniform base + lane*16.
__device__ __forceinline__ void load_lds16(const void* g, void* l) {
  auto gp = reinterpret_cast<const __attribute__((address_space(1))) unsigned int*>(
      reinterpret_cast<uintptr_t>(g));
  auto lp = reinterpret_cast<__attribute__((address_space(3))) unsigned int*>(
      reinterpret_cast<uintptr_t>(l));
  __builtin_amdgcn_global_load_lds(gp, lp, 16, 0, 0);
}

#define BAR() asm volatile("s_barrier" ::: "memory")
#define LGKM(N) do { asm volatile("s_waitcnt lgkmcnt(" #N ")" ::: "memory"); \
                     __builtin_amdgcn_sched_barrier(0); } while (0)
#define VMW(N) asm volatile("s_waitcnt vmcnt(" #N ")" ::: "memory")
#define SB0() __builtin_amdgcn_sched_barrier(0)

// ---------------------------------------------------------------------------
// Fused prep: blocks [0, OUTD+128) build Wcat/Acat; rest do x->bf16 + gating.
// ---------------------------------------------------------------------------
__global__ __launch_bounds__(256) void fused_prep_kernel(
    const float* __restrict__ x, const float* __restrict__ Wg,
    const float* __restrict__ W, const float* __restrict__ Bm,
    const float* __restrict__ Am, unsigned short* __restrict__ Wcat,
    unsigned short* __restrict__ Acat, unsigned short* __restrict__ Xcat,
    int* __restrict__ ridx, float* __restrict__ rw, float scaling) {
  __shared__ float red[32 * 257];
  __shared__ float lg[32];
  int tid = threadIdx.x;
  int bb = blockIdx.x;
  if (bb < OUTD) {
    const float4* src = (const float4*)(W + (size_t)bb * DIM_);
    unsigned short* dst = Wcat + (size_t)bb * KCAT;
#pragma unroll
    for (int j = 0; j < DIM_ / 1024; ++j) {
      float4 v = src[j * 256 + tid];
      ushort4 o; o.x = f2bf(v.x); o.y = f2bf(v.y); o.z = f2bf(v.z); o.w = f2bf(v.w);
      *(ushort4*)(dst + (size_t)(j * 256 + tid) * 4) = o;
    }
    if (tid < LORA_COLS) {
      int e = tid >> 4, r = tid & 15;
      dst[DIM_ + tid] = f2bf(scaling * Bm[((size_t)e * OUTD + bb) * NR + r]);
    }
    return;
  }
  if (bb < OUTD + LORA_COLS) {
    int i = bb - OUTD;  // 0..127  (A is [E,R,D] flat = [128][4096])
    const float4* src = (const float4*)(Am + (size_t)i * DIM_);
    unsigned short* dst = Acat + (size_t)i * DIM_;
#pragma unroll
    for (int j = 0; j < DIM_ / 1024; ++j) {
      float4 v = src[j * 256 + tid];
      ushort4 o; o.x = f2bf(v.x); o.y = f2bf(v.y); o.z = f2bf(v.z); o.w = f2bf(v.w);
      *(ushort4*)(dst + (size_t)(j * 256 + tid) * 4) = o;
    }
    return;
  }
  // ---- prep_x body ----
  int t0 = (bb - OUTD - LORA_COLS) * 4;
  float acc[4][8];
#pragma unroll
  for (int ti = 0; ti < 4; ++ti)
#pragma unroll
    for (int e = 0; e < 8; ++e) acc[ti][e] = 0.f;
  const float4* x4 = (const float4*)x;
  const float4* wg4 = (const float4*)Wg;
#pragma unroll
  for (int j = 0; j < 4; ++j) {
    int dpos = j * 256 + tid;
    float4 wg[8];
#pragma unroll
    for (int e = 0; e < 8; ++e) wg[e] = wg4[e * 1024 + dpos];
#pragma unroll
    for (int ti = 0; ti < 4; ++ti) {
      float4 v = x4[(size_t)(t0 + ti) * 1024 + dpos];
      ushort4 o; o.x = f2bf(v.x); o.y = f2bf(v.y); o.z = f2bf(v.z); o.w = f2bf(v.w);
      *(ushort4*)&Xcat[(size_t)(t0 + ti) * KCAT + (size_t)dpos * 4] = o;
#pragma unroll
      for (int e = 0; e < 8; ++e)
        acc[ti][e] += v.x * wg[e].x + v.y * wg[e].y + v.z * wg[e].z + v.w * wg[e].w;
    }
  }
#pragma unroll
  for (int p = 0; p < 32; ++p) red[p * 257 + tid] = acc[p >> 3][p & 7];
  __syncthreads();
  {
    int p = tid >> 3, part = tid & 7;
    float s = 0.f;
#pragma unroll
    for (int i = 0; i < 32; ++i) s += red[p * 257 + part * 32 + i];
    s += __shfl_xor(s, 1);
    s += __shfl_xor(s, 2);
    s += __shfl_xor(s, 4);
    if (part == 0) lg[p] = s;
  }
  __syncthreads();
  if (tid < 4) {
    float l[8];
#pragma unroll
    for (int e = 0; e < 8; ++e) l[e] = lg[tid * 8 + e];
    int i0 = 0; float m0 = l[0];
#pragma unroll
    for (int e = 1; e < 8; ++e) if (l[e] > m0) { m0 = l[e]; i0 = e; }
    int i1 = -1; float m1 = -3.4e38f;
#pragma unroll
    for (int e = 0; e < 8; ++e) if (e != i0 && l[e] > m1) { m1 = l[e]; i1 = e; }
    float w0 = 1.0f / (1.0f + expf(m1 - m0));
    int t = t0 + tid;
    ridx[t * 2] = i0; ridx[t * 2 + 1] = i1;
    rw[t * 2] = w0;  rw[t * 2 + 1] = 1.0f - w0;
  }
}

// ---------------------------------------------------------------------------
// m97-style 128x128 GEMM, fallback h-GEMM (MODE 1) if ws too small.
// ---------------------------------------------------------------------------
template <int MODE>
__global__ __launch_bounds__(256) void gemm_kernel(
    const unsigned short* __restrict__ Aop, const unsigned short* __restrict__ Bop,
    float* __restrict__ Cout, unsigned short* __restrict__ CoutBf,
    const float* __restrict__ bias, const int* __restrict__ ridx,
    const float* __restrict__ rw,
    int M, int N, int K, int lda, int ldb, int ldc) {
  __shared__ __align__(16) unsigned short lsA[128 * 32];
  __shared__ __align__(16) unsigned short lsB[128 * 32];
  int tid = threadIdx.x;
  int lane = tid & 63, wave = tid >> 6;
  int wm = wave >> 1, wn = wave & 1;
  int row0 = blockIdx.x * 128, col0 = blockIdx.y * 128;

  f32x4 acc[4][4];
#pragma unroll
  for (int a = 0; a < 4; ++a)
#pragma unroll
    for (int b = 0; b < 4; ++b) acc[a][b] = (f32x4){0.f, 0.f, 0.f, 0.f};

  int lrow = lane >> 2;
  int lcol = (lane & 3) << 3;
  int fr = lane & 15, fk = (lane >> 4) << 3;

  const unsigned short* gA0 = Aop + (size_t)(row0 + wave * 32 + lrow) * lda + lcol;
  const unsigned short* gA1 = Aop + (size_t)(row0 + wave * 32 + 16 + lrow) * lda + lcol;
  const unsigned short* gB0 = Bop + (size_t)(col0 + wave * 32 + lrow) * ldb + lcol;
  const unsigned short* gB1 = Bop + (size_t)(col0 + wave * 32 + 16 + lrow) * ldb + lcol;

  for (int k0 = 0; k0 < K; k0 += 32) {
    load_lds16(gA0 + k0, lsA + wave * 1024);
    load_lds16(gA1 + k0, lsA + wave * 1024 + 512);
    load_lds16(gB0 + k0, lsB + wave * 1024);
    load_lds16(gB1 + k0, lsB + wave * 1024 + 512);
    __syncthreads();
    short8 af[4], bfr[4];
#pragma unroll
    for (int mi = 0; mi < 4; ++mi)
      af[mi] = *(const short8*)&lsA[(wm * 64 + mi * 16 + fr) * 32 + fk];
#pragma unroll
    for (int ni = 0; ni < 4; ++ni)
      bfr[ni] = *(const short8*)&lsB[(wn * 64 + ni * 16 + fr) * 32 + fk];
#pragma unroll
    for (int mi = 0; mi < 4; ++mi)
#pragma unroll
      for (int ni = 0; ni < 4; ++ni)
        acc[mi][ni] = __builtin_amdgcn_mfma_f32_16x16x32_bf16(af[mi], bfr[ni], acc[mi][ni], 0, 0, 0);
    __syncthreads();
  }

  int fg = lane >> 4;
  if (MODE == 0) {
#pragma unroll
    for (int ni = 0; ni < 4; ++ni) {
      int col = col0 + wn * 64 + ni * 16 + fr;
      float bv = bias[col];
#pragma unroll
      for (int mi = 0; mi < 4; ++mi)
#pragma unroll
        for (int j = 0; j < 4; ++j) {
          int row = row0 + wm * 64 + mi * 16 + fg * 4 + j;
          Cout[(size_t)row * ldc + col] = acc[mi][ni][j] + bv;
        }
    }
  } else {
#pragma unroll
    for (int mi = 0; mi < 4; ++mi)
#pragma unroll
      for (int j = 0; j < 4; ++j) {
        int row = row0 + wm * 64 + mi * 16 + fg * 4 + j;
        int i0 = ridx[row * 2], i1 = ridx[row * 2 + 1];
        float w0 = rw[row * 2], w1 = rw[row * 2 + 1];
#pragma unroll
        for (int ni = 0; ni < 4; ++ni) {
          int col = wn * 64 + ni * 16 + fr;
          int e = col >> 4;
          float w = (e == i0) ? w0 : ((e == i1) ? w1 : 0.f);
          CoutBf[(size_t)row * ldc + col] = f2bf(w * acc[mi][ni][j]);
        }
      }
  }
}

// ---------------------------------------------------------------------------
// Split-K h-GEMM: Hpart (bf16) [s][8192][128] partial sums.
// ---------------------------------------------------------------------------
__global__ __launch_bounds__(256) void gemm_h_sk_kernel(
    const unsigned short* __restrict__ Aop,   // Xcat, lda = KCAT
    const unsigned short* __restrict__ Bop,   // Acat, ldb = DIM_
    unsigned short* __restrict__ Hpart) {
  __shared__ __align__(16) unsigned short lsA[128 * 32];
  __shared__ __align__(16) unsigned short lsB[128 * 32];
  int tid = threadIdx.x;
  int lane = tid & 63, wave = tid >> 6;
  int wm = wave >> 1, wn = wave & 1;
  int row0 = blockIdx.x * 128;
  int s = blockIdx.y;
  int kbeg = s * HKC;

  f32x4 acc[4][4];
#pragma unroll
  for (int a = 0; a < 4; ++a)
#pragma unroll
    for (int b = 0; b < 4; ++b) acc[a][b] = (f32x4){0.f, 0.f, 0.f, 0.f};

  int lrow = lane >> 2;
  int lcol = (lane & 3) << 3;
  int fr = lane & 15, fk = (lane >> 4) << 3;

  const unsigned short* gA0 = Aop + (size_t)(row0 + wave * 32 + lrow) * KCAT + lcol;
  const unsigned short* gA1 = Aop + (size_t)(row0 + wave * 32 + 16 + lrow) * KCAT + lcol;
  const unsigned short* gB0 = Bop + (size_t)(wave * 32 + lrow) * DIM_ + lcol;
  const unsigned short* gB1 = Bop + (size_t)(wave * 32 + 16 + lrow) * DIM_ + lcol;

  for (int k0 = kbeg; k0 < kbeg + HKC; k0 += 32) {
    load_lds16(gA0 + k0, lsA + wave * 1024);
    load_lds16(gA1 + k0, lsA + wave * 1024 + 512);
    load_lds16(gB0 + k0, lsB + wave * 1024);
    load_lds16(gB1 + k0, lsB + wave * 1024 + 512);
    __syncthreads();
    short8 af[4], bfr[4];
#pragma unroll
    for (int mi = 0; mi < 4; ++mi)
      af[mi] = *(const short8*)&lsA[(wm * 64 + mi * 16 + fr) * 32 + fk];
#pragma unroll
    for (int ni = 0; ni < 4; ++ni)
      bfr[ni] = *(const short8*)&lsB[(wn * 64 + ni * 16 + fr) * 32 + fk];
#pragma unroll
    for (int mi = 0; mi < 4; ++mi)
#pragma unroll
      for (int ni = 0; ni < 4; ++ni)
        acc[mi][ni] = __builtin_amdgcn_mfma_f32_16x16x32_bf16(af[mi], bfr[ni], acc[mi][ni], 0, 0, 0);
    __syncthreads();
  }

  int fg = lane >> 4;
  unsigned short* outp = Hpart + (size_t)s * TOKENS * 128;
#pragma unroll
  for (int ni = 0; ni < 4; ++ni) {
    int col = wn * 64 + ni * 16 + fr;
#pragma unroll
    for (int mi = 0; mi < 4; ++mi)
#pragma unroll
      for (int j = 0; j < 4; ++j) {
        int row = row0 + wm * 64 + mi * 16 + fg * 4 + j;
        outp[(size_t)row * 128 + col] = f2bf(acc[mi][ni][j]);
      }
  }
}

// ---------------------------------------------------------------------------
// Combine split-K bf16 partials, apply routing weights, write bf16 LoRA cols.
// ---------------------------------------------------------------------------
__global__ __launch_bounds__(256) void h_combine_kernel(
    const unsigned short* __restrict__ Hpart, const int* __restrict__ ridx,
    const float* __restrict__ rw, unsigned short* __restrict__ Xcat) {
  int gid = blockIdx.x * 256 + threadIdx.x;  // over TOKENS*128
  int t = gid >> 7, c = gid & 127;
  float s = 0.f;
#pragma unroll
  for (int i = 0; i < HSPLIT; ++i) s += bf2f(Hpart[(size_t)i * TOKENS * 128 + gid]);
  int e = c >> 4;
  int i0 = ridx[t * 2], i1 = ridx[t * 2 + 1];
  float w = (e == i0) ? rw[t * 2] : ((e == i1) ? rw[t * 2 + 1] : 0.f);
  Xcat[(size_t)t * KCAT + DIM_ + c] = f2bf(w * s);
}

// ---------------------------------------------------------------------------
// Main fused GEMM R13: R5/R12 skeleton, but the phase's ds_reads are issued
// BETWEEN two 8-MFMA half-clusters (inside the MFMA window) instead of at
// phase top. Hypothesis: R5's reads all sit in the inter-MFMA window, so the
// LDS pipe and matrix pipes alternate chip-wide (phase = LDS + MFMA in
// series, 1130 cy observed = 576 + 620 predicted). Feeding the LDS pipe
// mid-MFMA should overlap them. sched_barrier(0) fences pin the mid-reads.
// Read placement (mid of phase) -> consumer:
//   P1: aH,b1f -> P2, P3/P4   P2: a1L -> P3   P3: a1H -> P4
//   P4: aL',b0f'(buf1) -> P5  P5: aH',b1f'    P6: a1L'   P7: a1H'
//   P8: aL,b0f(buf0-next) -> next P1
// Wait ledger (FIFO at each phase's LGKM): P1(0) P2(4) P3(0) P4(0)
//   P5(0) P6(4) P7(0) P8(0).  Stage/VMW(6)/WAR ledger identical to R5.
// ---------------------------------------------------------------------------
#define RD_A4(dst, base, ks, mi0) do { \
  dst[0] = *(const short8*)((base) + (((mi0)+0)*2+(ks))*1024); \
  dst[1] = *(const short8*)((base) + (((mi0)+1)*2+(ks))*1024); \
  dst[2] = *(const short8*)((base) + (((mi0)+2)*2+(ks))*1024); \
  dst[3] = *(const short8*)((base) + (((mi0)+3)*2+(ks))*1024); } while (0)
#define RD_B4(dst, base, ks) do { \
  dst[0] = *(const short8*)((base) + 0*2048 + (ks)*1024); \
  dst[1] = *(const short8*)((base) + 1*2048 + (ks)*1024); \
  dst[2] = *(const short8*)((base) + 2*2048 + (ks)*1024); \
  dst[3] = *(const short8*)((base) + 3*2048 + (ks)*1024); } while (0)
// Half cluster: 8 MFMA (mi = mo..mo+1, all ni), acc rows (m0)+(mo)+mi
#define MFMA_H(a4, b4, m0, mo) do { \
  __builtin_amdgcn_s_setprio(1); \
  _Pragma("unroll") \
  for (int mi = 0; mi < 2; ++mi) { \
    _Pragma("unroll") \
    for (int ni = 0; ni < 4; ++ni) { \
      acc[(m0)+(mo)+mi][ni] = __builtin_amdgcn_mfma_f32_16x16x32_bf16( \
          b4[ni], a4[(mo)+mi], acc[(m0)+(mo)+mi][ni], 0, 0, 0); } } \
  __builtin_amdgcn_s_setprio(0); } while (0)
#define STAGE(srcp, kofs, dst) do { \
  load_lds16((srcp) + (kofs), (dst)); \
  load_lds16((srcp) + (kofs) + 32, (dst) + 1024); } while (0)

__global__ __launch_bounds__(512, 2) void gemm256_kernel(
    const unsigned short* __restrict__ Aop,   // Xcat [8192][KCAT]
    const unsigned short* __restrict__ Bop,   // Wcat [4096][KCAT]
    float* __restrict__ Cout, const float* __restrict__ bias) {
  extern __shared__ char lds[];
  const int tid = threadIdx.x;
  const int lane = tid & 63, wave = tid >> 6;
  const int wm = wave >> 2, wn = wave & 3;   // 2 x 4 waves; per-wave out 128x64
  const int fr = lane & 15, kg = lane >> 4;

  // XCD-bijective block swizzle (512 % 8 == 0)
  const int bid = blockIdx.x;
  const int swz = (bid & 7) * 64 + (bid >> 3);
  const int mt = swz >> 4, nt = swz & 15;    // 32 x 16 tiles
  const int row0 = mt * 256, nt0 = nt * 256;
  const int col0 = nt0;

  // ---- stage source pointers (per-thread, st_16x32 pre-swizzled cols) ----
  const int srow = lane >> 2;                                  // 0..15
  const int scol = ((lane & 3) * 8) ^ (((lane >> 5) & 1) * 16);
  const unsigned short* sA0 = Aop + (size_t)(row0 +       wave * 16 + srow) * KCAT + scol;
  const unsigned short* sA1 = Aop + (size_t)(row0 + 128 + wave * 16 + srow) * KCAT + scol;
  const unsigned short* sB0 = Bop + (size_t)(col0 +       wave * 16 + srow) * KCAT + scol;
  const unsigned short* sB1 = Bop + (size_t)(col0 + 128 + wave * 16 + srow) * KCAT + scol;

  // ---- LDS dest bases (wave-uniform; lane*16 added by HW) ----
  char* dA0b0 = lds +      0 + wave * 2048;
  char* dA1b0 = lds +  16384 + wave * 2048;
  char* dB0b0 = lds +  32768 + wave * 2048;
  char* dB1b0 = lds +  49152 + wave * 2048;
  char* dA0b1 = dA0b0 + 65536;
  char* dA1b1 = dA1b0 + 65536;
  char* dB0b1 = dB0b0 + 65536;
  char* dB1b1 = dB1b0 + 65536;

  // ---- ds_read bases (swizzled) ----
  const int swzo = (kg * 16) ^ ((fr >> 3) << 5);
  const char* rdA0 = lds + wm * 16384 + fr * 64 + swzo;
  const char* rdA1 = rdA0 + 65536;
  const char* rdB0 = lds + 32768 + (wn >> 1) * 16384 + (wn & 1) * 8192 + fr * 64 + swzo;
  const char* rdB1 = rdB0 + 65536;

  f32x4 acc[8][4];
#pragma unroll
  for (int a = 0; a < 8; ++a)
#pragma unroll
    for (int b = 0; b < 4; ++b) acc[a][b] = (f32x4){0.f, 0.f, 0.f, 0.f};

  short8 aL[4], aH[4], a1L[4], a1H[4], b0f[4], b1f[4];

  // ---- prologue: tile0 full -> buf0; tile1 {B0,B1,A0} -> buf1 (A1b1 at P1);
  //      VMW(6) drains the 8 tile0 loads; preload P1 operands ----
  STAGE(sA0, 0, dA0b0); STAGE(sA1, 0, dA1b0);
  STAGE(sB0, 0, dB0b0); STAGE(sB1, 0, dB1b0);
  STAGE(sB0, 64, dB0b1); STAGE(sB1, 64, dB1b1); STAGE(sA0, 64, dA0b1);
  VMW(6);
  BAR();
  RD_A4(aL, rdA0, 0, 0); RD_B4(b0f, rdB0, 0);

  // ---- main loop: 32 iterations, tile pairs (0,1)..(62,63) ----
  for (int i = 0; i < NTILES / 2 - 1; ++i) {
    const int k1 = (2 * i + 1) * 64, k2 = k1 + 64, k3 = k1 + 128;
    // P1: MFMA(aL,b0f) rows 0-3; mid-read aH,b1f; stage A1b1@k1
    STAGE(sA1, k1, dA1b1);
    BAR(); LGKM(0);
    MFMA_H(aL, b0f, 0, 0);
    SB0(); RD_A4(aH, rdA0, 0, 4); RD_B4(b1f, rdB0, 1); SB0();
    MFMA_H(aL, b0f, 0, 2);
    BAR();
    // P2: MFMA(aH,b0f) rows 4-7; mid-read a1L; stage B0b0@k2
    STAGE(sB0, k2, dB0b0);
    BAR(); LGKM(4);
    MFMA_H(aH, b0f, 4, 0);
    SB0(); RD_A4(a1L, rdA0, 1, 0); SB0();
    MFMA_H(aH, b0f, 4, 2);
    BAR();
    // P3: MFMA(a1L,b1f) rows 0-3; mid-read a1H; stage B1b0@k2
    STAGE(sB1, k2, dB1b0);
    BAR(); LGKM(0);
    MFMA_H(a1L, b1f, 0, 0);
    SB0(); RD_A4(a1H, rdA0, 1, 4); SB0();
    MFMA_H(a1L, b1f, 0, 2);
    BAR();
    // P4: stage A0b0@k2; VMW(6) -> buf1 tile 2i+1 ready; mid-read its q0
    STAGE(sA0, k2, dA0b0);
    VMW(6);
    BAR(); LGKM(0);
    MFMA_H(a1H, b1f, 4, 0);
    SB0(); RD_A4(aL, rdA1, 0, 0); RD_B4(b0f, rdB1, 0); SB0();
    MFMA_H(a1H, b1f, 4, 2);
    BAR();
    // P5: tile 2i+1 (buf1); mid-read aH,b1f; stage A1b0@k2
    STAGE(sA1, k2, dA1b0);
    BAR(); LGKM(0);
    MFMA_H(aL, b0f, 0, 0);
    SB0(); RD_A4(aH, rdA1, 0, 4); RD_B4(b1f, rdB1, 1); SB0();
    MFMA_H(aL, b0f, 0, 2);
    BAR();
    // P6: stage B0b1@k3
    STAGE(sB0, k3, dB0b1);
    BAR(); LGKM(4);
    MFMA_H(aH, b0f, 4, 0);
    SB0(); RD_A4(a1L, rdA1, 1, 0); SB0();
    MFMA_H(aH, b0f, 4, 2);
    BAR();
    // P7: stage B1b1@k3
    STAGE(sB1, k3, dB1b1);
    BAR(); LGKM(0);
    MFMA_H(a1L, b1f, 0, 0);
    SB0(); RD_A4(a1H, rdA1, 1, 4); SB0();
    MFMA_H(a1L, b1f, 0, 2);
    BAR();
    // P8: stage A0b1@k3; VMW(6) -> buf0 tile 2i+2 ready; mid-read its q0
    STAGE(sA0, k3, dA0b1);
    VMW(6);
    BAR(); LGKM(0);
    MFMA_H(a1H, b1f, 4, 0);
    SB0(); RD_A4(aL, rdA0, 0, 0); RD_B4(b0f, rdB0, 0); SB0();
    MFMA_H(a1H, b1f, 4, 2);
    BAR();
  }

  // ---- epilogue: tile 64 (buf0; stage A1b1@65), tile 65 (buf1) ----
  {
    const int k65 = 65 * 64;
    // E1
    STAGE(sA1, k65, dA1b1);
    BAR(); LGKM(0);
    MFMA_H(aL, b0f, 0, 0);
    SB0(); RD_A4(aH, rdA0, 0, 4); RD_B4(b1f, rdB0, 1); SB0();
    MFMA_H(aL, b0f, 0, 2);
    BAR();
    // E2
    BAR(); LGKM(4);
    MFMA_H(aH, b0f, 4, 0);
    SB0(); RD_A4(a1L, rdA0, 1, 0); SB0();
    MFMA_H(aH, b0f, 4, 2);
    BAR();
    // E3
    BAR(); LGKM(0);
    MFMA_H(a1L, b1f, 0, 0);
    SB0(); RD_A4(a1H, rdA0, 1, 4); SB0();
    MFMA_H(a1L, b1f, 0, 2);
    BAR();
    // E4: drain ALL stages; buf1 tile 65 complete
    VMW(0);
    BAR(); LGKM(0);
    MFMA_H(a1H, b1f, 4, 0);
    SB0(); RD_A4(aL, rdA1, 0, 0); RD_B4(b0f, rdB1, 0); SB0();
    MFMA_H(a1H, b1f, 4, 2);
    BAR();
    // tile 65 (no stages, no barriers)
    LGKM(0);
    MFMA_H(aL, b0f, 0, 0); MFMA_H(aL, b0f, 0, 2);
    RD_A4(aH, rdA1, 0, 4); RD_B4(b1f, rdB1, 1);
    LGKM(0);
    MFMA_H(aH, b0f, 4, 0); MFMA_H(aH, b0f, 4, 2);
    RD_A4(a1L, rdA1, 1, 0); RD_A4(a1H, rdA1, 1, 4);
    LGKM(4);
    MFMA_H(a1L, b1f, 0, 0); MFMA_H(a1L, b1f, 0, 2);
    LGKM(0);
    MFMA_H(a1H, b1f, 4, 0); MFMA_H(a1H, b1f, 4, 2);
  }

  // ---- C write (transposed fragments: lane holds 4 consecutive cols) ----
#pragma unroll
  for (int ni = 0; ni < 4; ++ni) {
    int colb = col0 + wn * 64 + ni * 16 + kg * 4;
    float4 bv = *(const float4*)&bias[colb];
#pragma unroll
    for (int mi = 0; mi < 8; ++mi) {
      int row = row0 + wm * 128 + mi * 16 + fr;
      float4 v;
      v.x = acc[mi][ni][0] + bv.x;
      v.y = acc[mi][ni][1] + bv.y;
      v.z = acc[mi][ni][2] + bv.z;
      v.w = acc[mi][ni][3] + bv.w;
      *(float4*)&Cout[(size_t)row * OUTD + colb] = v;
    }
  }
}

// ---------------------------------------------------------------------------
extern "C" void kernel_launch(void* const* d_in, const int* in_sizes, int n_in,
                              void* d_out, int out_size, void* d_ws, size_t ws_size,
                              hipStream_t stream) {
  const float* x  = (const float*)d_in[0];
  const float* Wb = (const float*)d_in[1];
  const float* bb = (const float*)d_in[2];
  const float* Wg = (const float*)d_in[3];
  const float* Am = (const float*)d_in[4];
  const float* Bm = (const float*)d_in[5];
  float* out = (float*)d_out;

  unsigned short* Wcat = (unsigned short*)d_ws;                 // [OUTD][KCAT]
  unsigned short* Xcat = Wcat + (size_t)OUTD * KCAT;            // [TOKENS][KCAT]
  unsigned short* Acat = Xcat + (size_t)TOKENS * KCAT;          // [128][DIM]
  int*   ridx = (int*)(Acat + (size_t)LORA_COLS * DIM_);        // [TOKENS][2]
  float* rw   = (float*)(ridx + (size_t)TOKENS * 2);            // [TOKENS][2]
  unsigned short* Hpart = (unsigned short*)(rw + (size_t)TOKENS * 2); // [S][TOKENS][128] bf16

  const size_t ws_needed = (size_t)((char*)(Hpart + (size_t)HSPLIT * TOKENS * 128)
                                    - (char*)d_ws);
  const bool use_splitk = (ws_size >= ws_needed);

  const float scaling = 16.0f / (float)NR;  // = 1.0

  hipFuncSetAttribute((const void*)gemm256_kernel,
                      hipFuncAttributeMaxDynamicSharedMemorySize, 131072);

  fused_prep_kernel<<<dim3(OUTD + LORA_COLS + TOKENS / 4), dim3(256), 0, stream>>>(
      x, Wg, Wb, Bm, Am, Wcat, Acat, Xcat, ridx, rw, scaling);
  if (use_splitk) {
    gemm_h_sk_kernel<<<dim3(TOKENS / 128, HSPLIT), dim3(256), 0, stream>>>(
        Xcat, Acat, Hpart);
    h_combine_kernel<<<dim3(TOKENS * 128 / 256), dim3(256), 0, stream>>>(
        Hpart, ridx, rw, Xcat);
  } else {
    gemm_kernel<1><<<dim3(TOKENS / 128, 1), dim3(256), 0, stream>>>(
        Xcat, Acat, (float*)nullptr, Xcat + DIM_, (const float*)nullptr,
        ridx, rw, TOKENS, LORA_COLS, DIM_, KCAT, DIM_, KCAT);
  }
  // main fused GEMM: 256x256 8-phase, mid-MFMA read interleave
  gemm256_kernel<<<dim3(512), dim3(512), 131072, stream>>>(Xcat, Wcat, out, bb);
}